// Round 3
// baseline (655.285 us; speedup 1.0000x reference)
//
#include <hip/hip_runtime.h>
#include <hip/hip_bf16.h>

#define HH 32
#define WW 64
#define HWSZ 2048
#define ENC 1024
#define VOCAB 5000

typedef __attribute__((ext_vector_type(8))) short short8;
typedef __attribute__((ext_vector_type(4))) float f32x4;

__device__ __forceinline__ float sigm(float x) { return 1.0f / (1.0f + expf(-x)); }

__device__ __forceinline__ unsigned short f2bf(float x) {
    unsigned u = __float_as_uint(x);
    unsigned r = (u + 0x7fff + ((u >> 16) & 1)) >> 16;
    return (unsigned short)r;
}

// ---------------- K0: fused prep: ua->bf16 | wr restage | attsum | BN coef ------
__global__ __launch_bounds__(256) void k_prep(
    const float* __restrict__ ua_w, unsigned short* __restrict__ ub,
    const float* __restrict__ cw, unsigned short* __restrict__ wr,
    const float* __restrict__ att_in, const float* __restrict__ dec,
    const float* __restrict__ c1w, const float* __restrict__ c1b,
    float* __restrict__ out_attsum,
    const float* __restrict__ wb, const float* __restrict__ g,
    const float* __restrict__ bb, const float* __restrict__ rm,
    const float* __restrict__ rv, float* __restrict__ cs, float* __restrict__ csh)
{
    int blk = blockIdx.x, t = threadIdx.x;
    if (blk < 1024) {                       // ua_w fp32 -> bf16
        int idx = blk * 256 + t;
        ub[idx] = f2bf(ua_w[idx]);
    } else if (blk < 1280) {                // convtan_w -> w_r[tap][o][ci] bf16
        int idx = (blk - 1024) * 256 + t;   // 65536 = (o,ci)
        const float* p = cw + (size_t)idx * 9;
        #pragma unroll
        for (int k = 0; k < 9; ++k) wr[k * 65536 + idx] = f2bf(p[k]);
    } else if (blk < 1408) {                // att_sum = attention_sum + conv1(dec)
        int idx = (blk - 1280) * 256 + t;   // < 32768
        int b = idx >> 11, hw = idx & 2047;
        int h = hw >> 6, w = hw & 63;
        float s = c1b[0];
        #pragma unroll
        for (int dy = 0; dy < 3; ++dy) {
            int hh = h + dy - 1;
            if ((unsigned)hh < (unsigned)HH) {
                #pragma unroll
                for (int dx = 0; dx < 3; ++dx) {
                    int wi = w + dx - 1;
                    if ((unsigned)wi < (unsigned)WW)
                        s += dec[b * HWSZ + hh * WW + wi] * c1w[dy * 3 + dx];
                }
            }
        }
        out_attsum[idx] = att_in[idx] + s;
    } else {                                // BN coef fold
        int c = t;
        float s = g[c] * rsqrtf(rv[c] + 1e-5f);
        cs[c] = s;
        csh[c] = (wb[c] - rm[c]) * s + bb[c];
    }
}

// ---------------- K1a: gi/gh for GRU1, wide (j,b) mapping -----------------------
__global__ __launch_bounds__(256) void k_front_a(
    const int* __restrict__ input_a, const float* __restrict__ input_hidden,
    const float* __restrict__ emb_w,
    const float* __restrict__ w_ih, const float* __restrict__ w_hh,
    const float* __restrict__ b_ih, const float* __restrict__ b_hh,
    float* __restrict__ gi, float* __restrict__ gh)
{
    int gid = blockIdx.x * 256 + threadIdx.x;   // 48 blocks -> 12288 = 768*16
    int j = gid >> 4, b = gid & 15;
    int ia = input_a[b];
    const float* e  = emb_w + (size_t)ia * 256;
    const float* h0 = input_hidden + b * 256;
    const float* wi = w_ih + (size_t)j * 256;
    const float* wh = w_hh + (size_t)j * 256;
    float si = 0.f, sh = 0.f;
    for (int k = 0; k < 256; ++k) { si += e[k] * wi[k]; sh += h0[k] * wh[k]; }
    gi[j * 16 + b] = si + b_ih[j];
    gh[j * 16 + b] = sh + b_hh[j];
}

// ---------------- K1b: GRU1 gates + emb passthrough + fc1 -> addc (fused) -------
__global__ __launch_bounds__(256) void k_frontbc(
    const int* __restrict__ input_a, const float* __restrict__ emb_w,
    const float* __restrict__ input_hidden,
    const float* __restrict__ gi, const float* __restrict__ gh,
    const float* __restrict__ fc1_w, const float* __restrict__ fc1_b,
    const float* __restrict__ ua_b, const float* __restrict__ uf_b,
    float* __restrict__ st, float* __restrict__ embv, float* __restrict__ addc)
{
    __shared__ float st_s[256];
    int b = blockIdx.x, i = threadIdx.x;
    float r = sigm(gi[i * 16 + b] + gh[i * 16 + b]);
    float z = sigm(gi[(256 + i) * 16 + b] + gh[(256 + i) * 16 + b]);
    float n = tanhf(gi[(512 + i) * 16 + b] + r * gh[(512 + i) * 16 + b]);
    float h0 = input_hidden[b * 256 + i];
    float v = (1.f - z) * n + z * h0;
    st_s[i] = v;
    st[b * 256 + i] = v;
    embv[b * 256 + i] = emb_w[(size_t)input_a[b] * 256 + i];
    __syncthreads();
    int c = i;
    const float* w = fc1_w + (size_t)c * 256;
    float acc = 0.f;
    for (int k = 0; k < 256; ++k) acc += st_s[k] * w[k];
    addc[b * 256 + c] = acc + fc1_b[c] + ua_b[c] + uf_b[c];
}

// ---------------- K3: et-GEMM via MFMA, 512 thr, KC=64, swizzled Bs -------------
// out[c=256][hw=64/block] = ua[c][k=1024] @ enc[k][hw]; NHWC bf16 out.
__global__ __launch_bounds__(512) void k_et(
    const float* __restrict__ enc, const unsigned short* __restrict__ ua_bf,
    const float* __restrict__ addc, const float* __restrict__ uf_w,
    const float* __restrict__ attsum, unsigned short* __restrict__ et)
{
    __shared__ unsigned short Bs[64 * 64];   // [pixel][k-chunk 64], XOR swizzle, 8KB
    int t = threadIdx.x;
    int hw0 = blockIdx.x * 64, b = blockIdx.y;
    int wv = t >> 6;
    int l15 = t & 15, quad = (t >> 4) & 3;
    int wy = wv >> 1, wx = wv & 1;           // wave tile: M=64 (wy), N=32 (wx)
    f32x4 acc[4][2];
    #pragma unroll
    for (int i = 0; i < 4; ++i)
        #pragma unroll
        for (int j = 0; j < 2; ++j) acc[i][j] = (f32x4)0.f;

    int sww = t & 63;                        // staging pixel
    int sk  = (t >> 6) * 8;                  // staging k offset (0..56)
    int scol = ((sk >> 3) ^ (sww & 7)) * 8;  // bank swizzle
    const float* encb = enc + (size_t)b * ENC * HWSZ + hw0 + sww;

    for (int k0 = 0; k0 < ENC; k0 += 64) {
        __syncthreads();
        {   // stage 64k x 64hw fp32 -> bf16 transposed (coalesced 256B rows)
            const float* ep = encb + (size_t)(k0 + sk) * HWSZ;
            short8 v;
            #pragma unroll
            for (int i = 0; i < 8; ++i) v[i] = (short)f2bf(ep[(size_t)i * HWSZ]);
            *(short8*)(Bs + sww * 64 + scol) = v;
        }
        __syncthreads();
        #pragma unroll
        for (int kh = 0; kh < 64; kh += 32) {
            short8 af[4], bfr[2];
            #pragma unroll
            for (int mt = 0; mt < 4; ++mt)
                af[mt] = *(const short8*)(ua_bf +
                    (size_t)(wy * 64 + mt * 16 + l15) * ENC + k0 + kh + quad * 8);
            #pragma unroll
            for (int nt = 0; nt < 2; ++nt) {
                int n = wx * 32 + nt * 16 + l15;
                int col = (((kh + quad * 8) >> 3) ^ (n & 7)) * 8;
                bfr[nt] = *(const short8*)(Bs + n * 64 + col);
            }
            #pragma unroll
            for (int mt = 0; mt < 4; ++mt)
                #pragma unroll
                for (int nt = 0; nt < 2; ++nt)
                    acc[mt][nt] = __builtin_amdgcn_mfma_f32_16x16x32_bf16(
                        af[mt], bfr[nt], acc[mt][nt], 0, 0, 0);
        }
    }
    // epilogue: + addc[c] + attsum[hw]*uf_w[c], store NHWC bf16
    float at[2];
    #pragma unroll
    for (int nt = 0; nt < 2; ++nt)
        at[nt] = attsum[b * HWSZ + hw0 + wx * 32 + nt * 16 + l15];
    #pragma unroll
    for (int mt = 0; mt < 4; ++mt) {
        int cb = wy * 64 + mt * 16 + quad * 4;
        float ad[4], uw[4];
        #pragma unroll
        for (int r = 0; r < 4; ++r) { ad[r] = addc[b * 256 + cb + r]; uw[r] = uf_w[cb + r]; }
        #pragma unroll
        for (int nt = 0; nt < 2; ++nt) {
            int pix = hw0 + wx * 32 + nt * 16 + l15;
            ushort4 pk;
            pk.x = f2bf(acc[mt][nt][0] + ad[0] + at[nt] * uw[0]);
            pk.y = f2bf(acc[mt][nt][1] + ad[1] + at[nt] * uw[1]);
            pk.z = f2bf(acc[mt][nt][2] + ad[2] + at[nt] * uw[2]);
            pk.w = f2bf(acc[mt][nt][3] + ad[3] + at[nt] * uw[3]);
            *(ushort4*)(et + (size_t)(b * HWSZ + pix) * 256 + cb) = pk;
        }
    }
}

// ---------------- K4: conv3x3 implicit-GEMM MFMA + BN + tanh + v-dot, 512 thr ---
__global__ __launch_bounds__(512) void k_conv(
    const unsigned short* __restrict__ et, const unsigned short* __restrict__ wr,
    const float* __restrict__ cs, const float* __restrict__ csh,
    const float* __restrict__ v_w, float* __restrict__ e_out)
{
    __shared__ unsigned short Ls[66 * 264];  // [pixel 0..65][ci 256 pad->264] 34.8KB
    __shared__ float red[64][17];
    int t = threadIdx.x;
    int h = blockIdx.x, b = blockIdx.y;
    int wv = t >> 6, l15 = t & 15, quad = (t >> 4) & 3;
    int wy = wv >> 1, wx = wv & 1;           // wave tile: M=64, N=32
    f32x4 acc[4][2];
    #pragma unroll
    for (int i = 0; i < 4; ++i)
        #pragma unroll
        for (int j = 0; j < 2; ++j) acc[i][j] = (f32x4)0.f;

    for (int dy = 0; dy < 3; ++dy) {
        int hr = h + dy - 1;
        if ((unsigned)hr >= (unsigned)HH) continue;   // block-uniform
        __syncthreads();
        const unsigned short* rowp = et + (size_t)(b * HH + hr) * WW * 256;
        for (int idx = t; idx < 2112; idx += 512) {   // 66 pixels x 32 chunks
            int p = idx >> 5, s = idx & 31;
            short8 v;
            if (p == 0 || p == 65) v = (short8)0;
            else v = *(const short8*)(rowp + (p - 1) * 256 + s * 8);
            *(short8*)(Ls + p * 264 + s * 8) = v;
        }
        __syncthreads();
        for (int dx = 0; dx < 3; ++dx) {
            int tap = dy * 3 + dx;
            const unsigned short* wrt = wr + (size_t)tap * 65536;
            #pragma unroll 1
            for (int kc = 0; kc < 8; ++kc) {
                short8 af[4], bfr[2];
                #pragma unroll
                for (int mt = 0; mt < 4; ++mt)
                    af[mt] = *(const short8*)(wrt +
                        (size_t)(wy * 64 + mt * 16 + l15) * 256 + kc * 32 + quad * 8);
                #pragma unroll
                for (int nt = 0; nt < 2; ++nt) {
                    int wrow = wx * 32 + nt * 16 + l15 + dx;   // 0..65, pads zero
                    bfr[nt] = *(const short8*)(Ls + wrow * 264 + kc * 32 + quad * 8);
                }
                #pragma unroll
                for (int mt = 0; mt < 4; ++mt)
                    #pragma unroll
                    for (int nt = 0; nt < 2; ++nt)
                        acc[mt][nt] = __builtin_amdgcn_mfma_f32_16x16x32_bf16(
                            af[mt], bfr[nt], acc[mt][nt], 0, 0, 0);
            }
        }
    }
    // epilogue: y = acc*cs + csh; partial e = sum tanh(y)*v_w over this lane's c
    float p[2] = {0.f, 0.f};
    #pragma unroll
    for (int mt = 0; mt < 4; ++mt) {
        int cb = wy * 64 + mt * 16 + quad * 4;
        #pragma unroll
        for (int r = 0; r < 4; ++r) {
            float sc = cs[cb + r], sh = csh[cb + r], vw = v_w[cb + r];
            #pragma unroll
            for (int nt = 0; nt < 2; ++nt) {
                float x = acc[mt][nt][r] * sc + sh;
                p[nt] += tanhf(x) * vw;
            }
        }
    }
    __syncthreads();
    #pragma unroll
    for (int nt = 0; nt < 2; ++nt)
        red[wx * 32 + nt * 16 + l15][wy * 4 + quad] = p[nt];
    __syncthreads();
    if (t < 64) {
        float s = 0.f;
        #pragma unroll
        for (int i = 0; i < 16; ++i) s += red[t][i];
        e_out[(b * HH + h) * WW + t] = s;
    }
}

// ---------------- K5: softmax over masked e -> alpha ----------------------------
__global__ __launch_bounds__(256) void k_alpha(
    const float* __restrict__ e_acc, const float* __restrict__ v_b,
    const int* __restrict__ h_mask, const int* __restrict__ w_mask,
    float* __restrict__ alpha_ws, float* __restrict__ alpha_out)
{
    __shared__ float rbuf[4];
    int b = blockIdx.x, t = threadIdx.x;
    int hm = h_mask[b], wm = w_mask[b];
    float vb = v_b[0];
    float vals[8];
    float psum = 0.f;
    #pragma unroll
    for (int u = 0; u < 8; ++u) {
        int s = u * 256 + t;
        int h = s >> 6, w = s & 63;
        float e = e_acc[b * HWSZ + s] + vb;
        float ex = (h < hm && w < wm) ? expf(e) : 0.f;
        vals[u] = ex;
        psum += ex;
    }
    for (int off = 1; off < 64; off <<= 1) psum += __shfl_xor(psum, off, 64);
    if ((t & 63) == 0) rbuf[t >> 6] = psum;
    __syncthreads();
    float tot = rbuf[0] + rbuf[1] + rbuf[2] + rbuf[3] + 1e-8f;
    float inv = 1.f / tot;
    #pragma unroll
    for (int u = 0; u < 8; ++u) {
        int s = u * 256 + t;
        float a = vals[u] * inv;
        alpha_ws[b * HWSZ + s] = a;
        alpha_out[b * HWSZ + s] = a;
    }
}

// ---------------- K6: ct[b,c] = sum_hw alpha * enc  (wave per channel) ----------
__global__ __launch_bounds__(256) void k_ct(
    const float* __restrict__ enc, const float* __restrict__ alpha,
    float* __restrict__ ct)
{
    __shared__ float a_s[HWSZ];
    int b = blockIdx.y, cg = blockIdx.x, t = threadIdx.x;
    for (int s = t; s < HWSZ; s += 256) a_s[s] = alpha[b * HWSZ + s];
    __syncthreads();
    int wave = t >> 6, lane = t & 63;
    int c = cg * 4 + wave;
    const float* ep = enc + ((size_t)(b * ENC + c)) * HWSZ;
    float s = 0.f;
    for (int i = lane; i < HWSZ; i += 64) s += ep[i] * a_s[i];
    for (int off = 32; off; off >>= 1) s += __shfl_down(s, off, 64);
    if (lane == 0) ct[b * ENC + c] = s;
}

// ---------------- K7a: gi/gh for GRU2, wide (j,b) mapping -----------------------
__global__ __launch_bounds__(256) void k_gru2a(
    const float* __restrict__ ct, const float* __restrict__ st,
    const float* __restrict__ w_ih, const float* __restrict__ w_hh,
    const float* __restrict__ b_ih, const float* __restrict__ b_hh,
    float* __restrict__ gi, float* __restrict__ gh)
{
    int gid = blockIdx.x * 256 + threadIdx.x;  // 48 blocks
    int j = gid >> 4, b = gid & 15;
    const float* c = ct + b * ENC;
    const float* wi = w_ih + (size_t)j * ENC;
    float si = 0.f;
    for (int k = 0; k < ENC; ++k) si += c[k] * wi[k];
    const float* s = st + b * 256;
    const float* wh = w_hh + (size_t)j * 256;
    float sh = 0.f;
    for (int k = 0; k < 256; ++k) sh += s[k] * wh[k];
    gi[j * 16 + b] = si + b_ih[j];
    gh[j * 16 + b] = sh + b_hh[j];
}

// ---------------- K7b: GRU2 gates -> h2 / hidden_next ---------------------------
__global__ __launch_bounds__(256) void k_gru2b(
    const float* __restrict__ st, const float* __restrict__ gi,
    const float* __restrict__ gh, float* __restrict__ h2,
    float* __restrict__ out_hidden)
{
    int b = blockIdx.x, i = threadIdx.x;
    float r = sigm(gi[i * 16 + b] + gh[i * 16 + b]);
    float z = sigm(gi[(256 + i) * 16 + b] + gh[(256 + i) * 16 + b]);
    float n = tanhf(gi[(512 + i) * 16 + b] + r * gh[(512 + i) * 16 + b]);
    float v = (1.f - z) * n + z * st[b * 256 + i];
    h2[b * 256 + i] = v;
    out_hidden[b * 256 + i] = v;
}

// ---------------- K8: pre = h2@fc2^T + emb@emb2^T + ct@wc^T + biases ------------
__global__ __launch_bounds__(256) void k_pre(
    const float* __restrict__ h2, const float* __restrict__ emb,
    const float* __restrict__ ct,
    const float* __restrict__ fc2_w, const float* __restrict__ fc2_b,
    const float* __restrict__ emb2_w, const float* __restrict__ emb2_b,
    const float* __restrict__ wc_w, const float* __restrict__ wc_b,
    float* __restrict__ pre)
{
    int gid = blockIdx.x * 256 + threadIdx.x;  // 8 blocks -> 2048 = 128*16
    int j = gid >> 4, b = gid & 15;
    float s = fc2_b[j] + emb2_b[j] + wc_b[j];
    const float* x1 = h2 + b * 256;
    const float* w1 = fc2_w + (size_t)j * 256;
    for (int k = 0; k < 256; ++k) s += x1[k] * w1[k];
    const float* x2 = emb + b * 256;
    const float* w2 = emb2_w + (size_t)j * 256;
    for (int k = 0; k < 256; ++k) s += x2[k] * w2[k];
    const float* x3 = ct + b * ENC;
    const float* w3 = wc_w + (size_t)j * ENC;
    for (int k = 0; k < ENC; ++k) s += x3[k] * w3[k];
    pre[b * 128 + j] = s;
}

// ---------------- K9: logits = pre @ out_w^T + out_b, wide (j,b) ----------------
__global__ __launch_bounds__(256) void k_logits(
    const float* __restrict__ pre, const float* __restrict__ out_w,
    const float* __restrict__ out_b, float* __restrict__ logits)
{
    int gid = blockIdx.x * 256 + threadIdx.x;  // 313 blocks
    int j = gid >> 4, b = gid & 15;
    if (j >= VOCAB) return;
    const float* wr = out_w + (size_t)j * 128;
    const float* p = pre + b * 128;
    float s = out_b[j];
    for (int k = 0; k < 128; ++k) s += p[k] * wr[k];
    logits[b * VOCAB + j] = s;
}

// ---------------- K10: log_softmax ----------------------------------------------
__global__ __launch_bounds__(256) void k_lsm(
    const float* __restrict__ logits, float* __restrict__ out)
{
    __shared__ float buf[VOCAB];
    __shared__ float rbuf[4];
    int b = blockIdx.x, t = threadIdx.x;
    float mx = -1e30f;
    for (int s = t; s < VOCAB; s += 256) {
        float v = logits[b * VOCAB + s];
        buf[s] = v;
        mx = fmaxf(mx, v);
    }
    for (int off = 1; off < 64; off <<= 1) mx = fmaxf(mx, __shfl_xor(mx, off, 64));
    if ((t & 63) == 0) rbuf[t >> 6] = mx;
    __syncthreads();
    mx = fmaxf(fmaxf(rbuf[0], rbuf[1]), fmaxf(rbuf[2], rbuf[3]));
    __syncthreads();
    float se = 0.f;
    for (int s = t; s < VOCAB; s += 256) se += expf(buf[s] - mx);
    for (int off = 1; off < 64; off <<= 1) se += __shfl_xor(se, off, 64);
    if ((t & 63) == 0) rbuf[t >> 6] = se;
    __syncthreads();
    float lse = mx + logf(rbuf[0] + rbuf[1] + rbuf[2] + rbuf[3]);
    for (int s = t; s < VOCAB; s += 256) out[b * VOCAB + s] = buf[s] - lse;
}

extern "C" void kernel_launch(void* const* d_in, const int* in_sizes, int n_in,
                              void* d_out, int out_size, void* d_ws, size_t ws_size,
                              hipStream_t stream)
{
    const int*   input_a      = (const int*)d_in[0];
    const float* input_hidden = (const float*)d_in[1];
    const float* enc          = (const float*)d_in[2];
    const float* att_in       = (const float*)d_in[3];
    const float* dec_att      = (const float*)d_in[4];
    const int*   h_mask       = (const int*)d_in[5];
    const int*   w_mask       = (const int*)d_in[6];
    const float* emb_w        = (const float*)d_in[11];
    const float* g1_wih       = (const float*)d_in[12];
    const float* g1_whh       = (const float*)d_in[13];
    const float* g1_bih       = (const float*)d_in[14];
    const float* g1_bhh       = (const float*)d_in[15];
    const float* fc1_w        = (const float*)d_in[16];
    const float* fc1_b        = (const float*)d_in[17];
    const float* g2_wih       = (const float*)d_in[18];
    const float* g2_whh       = (const float*)d_in[19];
    const float* g2_bih       = (const float*)d_in[20];
    const float* g2_bhh       = (const float*)d_in[21];
    const float* out_w        = (const float*)d_in[22];
    const float* out_b        = (const float*)d_in[23];
    const float* emb2_w       = (const float*)d_in[24];
    const float* emb2_b       = (const float*)d_in[25];
    const float* c1w          = (const float*)d_in[26];
    const float* c1b          = (const float*)d_in[27];
    const float* ctw          = (const float*)d_in[28];
    const float* ctb          = (const float*)d_in[29];
    const float* fc2_w        = (const float*)d_in[30];
    const float* fc2_b        = (const float*)d_in[31];
    const float* ua_w         = (const float*)d_in[32];
    const float* ua_b         = (const float*)d_in[33];
    const float* uf_w         = (const float*)d_in[34];
    const float* uf_b         = (const float*)d_in[35];
    const float* v_w          = (const float*)d_in[36];
    const float* v_b          = (const float*)d_in[37];
    const float* wc_w         = (const float*)d_in[38];
    const float* wc_b         = (const float*)d_in[39];
    const float* bn_g         = (const float*)d_in[40];
    const float* bn_b         = (const float*)d_in[41];
    const float* bn_rm        = (const float*)d_in[42];
    const float* bn_rv        = (const float*)d_in[43];

    // output layout: log_softmax(16x5000) | hidden_next(16x256) | alpha(16x2048) | att_sum(16x2048)
    float* out        = (float*)d_out;
    float* out_logits = out;
    float* out_hidden = out + 80000;
    float* out_alpha  = out + 84096;
    float* out_attsum = out + 116864;

    // workspace layout
    char* ws = (char*)d_ws;
    unsigned short* et_t  = (unsigned short*)ws;                 // 16.78 MB (NHWC bf16)
    unsigned short* ua_bf = (unsigned short*)(ws + 16777216);    // 0.52 MB
    unsigned short* w_r   = (unsigned short*)(ws + 17301504);    // 1.18 MB
    float* f      = (float*)(ws + 18481152);
    float* st     = f;             // 4096
    float* embv   = f + 4096;      // 4096
    float* addc   = f + 8192;      // 4096
    float* e_ws   = f + 12288;     // 32768
    float* alpha  = f + 45056;     // 32768
    float* ct     = f + 77824;     // 16384
    float* h2     = f + 94208;     // 4096
    float* pre    = f + 98304;     // 2048
    float* logits = f + 100352;    // 80000
    float* gi1    = f + 180352;    // 12288
    float* gh1    = f + 192640;    // 12288
    float* gi2    = f + 204928;    // 12288
    float* gh2    = f + 217216;    // 12288
    float* cs     = f + 229504;    // 256
    float* csh    = f + 229760;    // 256

    k_prep<<<1409, 256, 0, stream>>>(ua_w, ua_bf, ctw, w_r,
                                     att_in, dec_att, c1w, c1b, out_attsum,
                                     ctb, bn_g, bn_b, bn_rm, bn_rv, cs, csh);
    k_front_a<<<48, 256, 0, stream>>>(input_a, input_hidden, emb_w,
                                      g1_wih, g1_whh, g1_bih, g1_bhh, gi1, gh1);
    k_frontbc<<<16, 256, 0, stream>>>(input_a, emb_w, input_hidden, gi1, gh1,
                                      fc1_w, fc1_b, ua_b, uf_b, st, embv, addc);

    k_et<<<dim3(32, 16), 512, 0, stream>>>(enc, ua_bf, addc, uf_w, out_attsum, et_t);
    k_conv<<<dim3(32, 16), 512, 0, stream>>>(et_t, w_r, cs, csh, v_w, e_ws);

    k_alpha<<<16, 256, 0, stream>>>(e_ws, v_b, h_mask, w_mask, alpha, out_alpha);
    k_ct<<<dim3(256, 16), 256, 0, stream>>>(enc, alpha, ct);
    k_gru2a<<<48, 256, 0, stream>>>(ct, st, g2_wih, g2_whh, g2_bih, g2_bhh, gi2, gh2);
    k_gru2b<<<16, 256, 0, stream>>>(st, gi2, gh2, h2, out_hidden);
    k_pre<<<8, 256, 0, stream>>>(h2, embv, ct, fc2_w, fc2_b, emb2_w, emb2_b,
                                 wc_w, wc_b, pre);
    k_logits<<<313, 256, 0, stream>>>(pre, out_w, out_b, logits);
    k_lsm<<<16, 256, 0, stream>>>(logits, out_logits);
}

// Round 4
// 579.310 us; speedup vs baseline: 1.1311x; 1.1311x over previous
//
#include <hip/hip_runtime.h>
#include <hip/hip_bf16.h>

#define HH 32
#define WW 64
#define HWSZ 2048
#define ENC 1024
#define VOCAB 5000

typedef __attribute__((ext_vector_type(8))) short short8;
typedef __attribute__((ext_vector_type(4))) float f32x4;

__device__ __forceinline__ float sigm(float x) { return 1.0f / (1.0f + expf(-x)); }

__device__ __forceinline__ unsigned short f2bf(float x) {
    unsigned u = __float_as_uint(x);
    unsigned r = (u + 0x7fff + ((u >> 16) & 1)) >> 16;
    return (unsigned short)r;
}

// ---------------- K0: fused prep: ua->bf16 | wr | attsum | coef | front_a | e=0 -
__global__ __launch_bounds__(256) void k_prep(
    const float* __restrict__ ua_w, unsigned short* __restrict__ ub,
    const float* __restrict__ cw, unsigned short* __restrict__ wr,
    const float* __restrict__ att_in, const float* __restrict__ dec,
    const float* __restrict__ c1w, const float* __restrict__ c1b,
    float* __restrict__ out_attsum,
    const float* __restrict__ wb, const float* __restrict__ g,
    const float* __restrict__ bb, const float* __restrict__ rm,
    const float* __restrict__ rv, float* __restrict__ cs, float* __restrict__ csh,
    const int* __restrict__ input_a, const float* __restrict__ input_hidden,
    const float* __restrict__ emb_w,
    const float* __restrict__ w_ih, const float* __restrict__ w_hh,
    const float* __restrict__ b_ih, const float* __restrict__ b_hh,
    float* __restrict__ gi, float* __restrict__ gh,
    float* __restrict__ e_zero)
{
    int blk = blockIdx.x, t = threadIdx.x;
    if (blk < 1024) {                       // ua_w fp32 -> bf16
        int idx = blk * 256 + t;
        ub[idx] = f2bf(ua_w[idx]);
    } else if (blk < 1280) {                // convtan_w -> w_r[tap][o][ci] bf16
        int idx = (blk - 1024) * 256 + t;   // 65536 = (o,ci)
        const float* p = cw + (size_t)idx * 9;
        #pragma unroll
        for (int k = 0; k < 9; ++k) wr[k * 65536 + idx] = f2bf(p[k]);
    } else if (blk < 1408) {                // att_sum = attention_sum + conv1(dec)
        int idx = (blk - 1280) * 256 + t;   // < 32768
        int b = idx >> 11, hw = idx & 2047;
        int h = hw >> 6, w = hw & 63;
        float s = c1b[0];
        #pragma unroll
        for (int dy = 0; dy < 3; ++dy) {
            int hh = h + dy - 1;
            if ((unsigned)hh < (unsigned)HH) {
                #pragma unroll
                for (int dx = 0; dx < 3; ++dx) {
                    int wi = w + dx - 1;
                    if ((unsigned)wi < (unsigned)WW)
                        s += dec[b * HWSZ + hh * WW + wi] * c1w[dy * 3 + dx];
                }
            }
        }
        out_attsum[idx] = att_in[idx] + s;
    } else if (blk == 1408) {               // BN coef fold
        int c = t;
        float s = g[c] * rsqrtf(rv[c] + 1e-5f);
        cs[c] = s;
        csh[c] = (wb[c] - rm[c]) * s + bb[c];
    } else if (blk < 1457) {                // GRU1 gi/gh (48 blocks)
        int gid = (blk - 1409) * 256 + t;   // 12288 = 768*16
        int j = gid >> 4, b = gid & 15;
        int ia = input_a[b];
        const float* e  = emb_w + (size_t)ia * 256;
        const float* h0 = input_hidden + b * 256;
        const float* wi = w_ih + (size_t)j * 256;
        const float* wh = w_hh + (size_t)j * 256;
        float si = 0.f, sh = 0.f;
        for (int k = 0; k < 256; ++k) { si += e[k] * wi[k]; sh += h0[k] * wh[k]; }
        gi[j * 16 + b] = si + b_ih[j];
        gh[j * 16 + b] = sh + b_hh[j];
    } else {                                // zero e accumulator (128 blocks)
        e_zero[(blk - 1457) * 256 + t] = 0.f;
    }
}

// ---------------- K1b: GRU1 gates + emb passthrough + fc1 -> addc (fused) -------
__global__ __launch_bounds__(256) void k_frontbc(
    const int* __restrict__ input_a, const float* __restrict__ emb_w,
    const float* __restrict__ input_hidden,
    const float* __restrict__ gi, const float* __restrict__ gh,
    const float* __restrict__ fc1_w, const float* __restrict__ fc1_b,
    const float* __restrict__ ua_b, const float* __restrict__ uf_b,
    float* __restrict__ st, float* __restrict__ embv, float* __restrict__ addc)
{
    __shared__ float st_s[256];
    int b = blockIdx.x, i = threadIdx.x;
    float r = sigm(gi[i * 16 + b] + gh[i * 16 + b]);
    float z = sigm(gi[(256 + i) * 16 + b] + gh[(256 + i) * 16 + b]);
    float n = tanhf(gi[(512 + i) * 16 + b] + r * gh[(512 + i) * 16 + b]);
    float h0 = input_hidden[b * 256 + i];
    float v = (1.f - z) * n + z * h0;
    st_s[i] = v;
    st[b * 256 + i] = v;
    embv[b * 256 + i] = emb_w[(size_t)input_a[b] * 256 + i];
    __syncthreads();
    int c = i;
    const float* w = fc1_w + (size_t)c * 256;
    float acc = 0.f;
    for (int k = 0; k < 256; ++k) acc += st_s[k] * w[k];
    addc[b * 256 + c] = acc + fc1_b[c] + ua_b[c] + uf_b[c];
}

// ---------------- K3: et-GEMM via MFMA, 256 thr, prefetched staging -------------
// out[c=256][hw=64/block] = ua[c][k=1024] @ enc[k][hw]; NHWC bf16 out.
__global__ __launch_bounds__(256) void k_et(
    const float* __restrict__ enc, const unsigned short* __restrict__ ua_bf,
    const float* __restrict__ addc, const float* __restrict__ uf_w,
    const float* __restrict__ attsum, unsigned short* __restrict__ et)
{
    __shared__ unsigned short Bs[64 * 40];   // [ww][kk(32, slot-rotated)]
    int t = threadIdx.x;
    int hw0 = blockIdx.x * 64, b = blockIdx.y;
    int lane = t & 63, wv = t >> 6;
    int l15 = t & 15, quad = (t >> 4) & 3;
    f32x4 acc[4][4];
    #pragma unroll
    for (int i = 0; i < 4; ++i)
        #pragma unroll
        for (int j = 0; j < 4; ++j) acc[i][j] = (f32x4)0.f;

    int sww = lane;                          // staging pixel
    int skk = wv * 8;                        // k-chunk base (8 of 32)
    int sslot = ((skk >> 3) + (sww >> 3)) & 3;
    const float* encb = enc + (size_t)b * ENC * HWSZ + hw0 + sww;

    // prefetch k0 = 0
    float pf[8];
    {
        const float* ep = encb + (size_t)skk * HWSZ;
        #pragma unroll
        for (int i = 0; i < 8; ++i) pf[i] = ep[(size_t)i * HWSZ];
    }
    for (int k0 = 0; k0 < ENC; k0 += 32) {
        short8 v;
        #pragma unroll
        for (int i = 0; i < 8; ++i) v[i] = (short)f2bf(pf[i]);
        __syncthreads();
        *(short8*)(Bs + sww * 40 + sslot * 8) = v;
        __syncthreads();
        if (k0 + 32 < ENC) {                 // issue next-tile loads (overlap MFMA)
            const float* ep = encb + (size_t)(k0 + 32 + skk) * HWSZ;
            #pragma unroll
            for (int i = 0; i < 8; ++i) pf[i] = ep[(size_t)i * HWSZ];
        }
        short8 af[4], bfr[4];
        #pragma unroll
        for (int mt = 0; mt < 4; ++mt)
            af[mt] = *(const short8*)(ua_bf +
                (size_t)(wv * 64 + mt * 16 + l15) * ENC + k0 + quad * 8);
        #pragma unroll
        for (int nt = 0; nt < 4; ++nt) {
            int n = nt * 16 + l15;
            int slot = (quad + (n >> 3)) & 3;
            bfr[nt] = *(const short8*)(Bs + n * 40 + slot * 8);
        }
        #pragma unroll
        for (int mt = 0; mt < 4; ++mt)
            #pragma unroll
            for (int nt = 0; nt < 4; ++nt)
                acc[mt][nt] = __builtin_amdgcn_mfma_f32_16x16x32_bf16(
                    af[mt], bfr[nt], acc[mt][nt], 0, 0, 0);
    }
    // epilogue: + addc[c] + attsum[hw]*uf_w[c], store NHWC bf16
    float at[4];
    #pragma unroll
    for (int nt = 0; nt < 4; ++nt) at[nt] = attsum[b * HWSZ + hw0 + nt * 16 + l15];
    #pragma unroll
    for (int mt = 0; mt < 4; ++mt) {
        int cb = wv * 64 + mt * 16 + quad * 4;
        float ad[4], uw[4];
        #pragma unroll
        for (int r = 0; r < 4; ++r) { ad[r] = addc[b * 256 + cb + r]; uw[r] = uf_w[cb + r]; }
        #pragma unroll
        for (int nt = 0; nt < 4; ++nt) {
            ushort4 pk;
            pk.x = f2bf(acc[mt][nt][0] + ad[0] + at[nt] * uw[0]);
            pk.y = f2bf(acc[mt][nt][1] + ad[1] + at[nt] * uw[1]);
            pk.z = f2bf(acc[mt][nt][2] + ad[2] + at[nt] * uw[2]);
            pk.w = f2bf(acc[mt][nt][3] + ad[3] + at[nt] * uw[3]);
            *(ushort4*)(et + (size_t)(b * HWSZ + hw0 + nt * 16 + l15) * 256 + cb) = pk;
        }
    }
}

// ---------------- K4: conv3x3 implicit-GEMM MFMA + BN + tanh + v-dot ------------
// Grid (h, c-half, b): block = [128 c_out][64 w]; 4 waves, M=32/wave, 8 MFMA/kc.
__global__ __launch_bounds__(256) void k_conv(
    const unsigned short* __restrict__ et, const unsigned short* __restrict__ wr,
    const float* __restrict__ cs, const float* __restrict__ csh,
    const float* __restrict__ v_w, float* __restrict__ e_out)
{
    __shared__ unsigned short Ls[66 * 264];  // [pixel 0..65][ci 256 pad->264]
    __shared__ float red[64][17];
    int t = threadIdx.x;
    int h = blockIdx.x, c0 = blockIdx.y * 128, b = blockIdx.z;
    int wv = t >> 6, l15 = t & 15, quad = (t >> 4) & 3;
    f32x4 acc[2][4];
    #pragma unroll
    for (int i = 0; i < 2; ++i)
        #pragma unroll
        for (int j = 0; j < 4; ++j) acc[i][j] = (f32x4)0.f;

    for (int dy = 0; dy < 3; ++dy) {
        int hr = h + dy - 1;
        if ((unsigned)hr >= (unsigned)HH) continue;   // block-uniform
        __syncthreads();
        const unsigned short* rowp = et + (size_t)(b * HH + hr) * WW * 256;
        for (int idx = t; idx < 2112; idx += 256) {   // 66 pixels x 32 chunks
            int p = idx >> 5, s = idx & 31;
            short8 v;
            if (p == 0 || p == 65) v = (short8)0;
            else v = *(const short8*)(rowp + (p - 1) * 256 + s * 8);
            *(short8*)(Ls + p * 264 + s * 8) = v;
        }
        __syncthreads();
        for (int dx = 0; dx < 3; ++dx) {
            int tap = dy * 3 + dx;
            const unsigned short* wrt = wr + (size_t)tap * 65536;
            #pragma unroll
            for (int kc = 0; kc < 8; ++kc) {
                short8 af[2], bfr[4];
                #pragma unroll
                for (int mt = 0; mt < 2; ++mt)
                    af[mt] = *(const short8*)(wrt +
                        (size_t)(c0 + wv * 32 + mt * 16 + l15) * 256 + kc * 32 + quad * 8);
                #pragma unroll
                for (int nt = 0; nt < 4; ++nt) {
                    int wrow = nt * 16 + l15 + dx;     // 0..65, pads zero
                    bfr[nt] = *(const short8*)(Ls + wrow * 264 + kc * 32 + quad * 8);
                }
                #pragma unroll
                for (int mt = 0; mt < 2; ++mt)
                    #pragma unroll
                    for (int nt = 0; nt < 4; ++nt)
                        acc[mt][nt] = __builtin_amdgcn_mfma_f32_16x16x32_bf16(
                            af[mt], bfr[nt], acc[mt][nt], 0, 0, 0);
            }
        }
    }
    // epilogue: y = acc*cs + csh; partial e = sum tanh(y)*v_w over this lane's c
    float p[4] = {0.f, 0.f, 0.f, 0.f};
    #pragma unroll
    for (int mt = 0; mt < 2; ++mt) {
        int cb = c0 + wv * 32 + mt * 16 + quad * 4;
        #pragma unroll
        for (int r = 0; r < 4; ++r) {
            float sc = cs[cb + r], sh = csh[cb + r], vw = v_w[cb + r];
            #pragma unroll
            for (int nt = 0; nt < 4; ++nt) {
                float x = acc[mt][nt][r] * sc + sh;
                p[nt] += tanhf(x) * vw;
            }
        }
    }
    __syncthreads();
    #pragma unroll
    for (int nt = 0; nt < 4; ++nt) red[nt * 16 + l15][wv * 4 + quad] = p[nt];
    __syncthreads();
    if (t < 64) {
        float s = 0.f;
        #pragma unroll
        for (int i = 0; i < 16; ++i) s += red[t][i];
        atomicAdd(&e_out[(b * HH + h) * WW + t], s);   // two c-halves accumulate
    }
}

// ---------------- K5+K6 fused: softmax(e)->alpha (LDS) + ct reduction -----------
__global__ __launch_bounds__(256) void k_ctalpha(
    const float* __restrict__ enc, const float* __restrict__ e_acc,
    const float* __restrict__ v_b,
    const int* __restrict__ h_mask, const int* __restrict__ w_mask,
    float* __restrict__ alpha_out, float* __restrict__ ct)
{
    __shared__ float a_s[HWSZ];
    __shared__ float rbuf[4];
    int b = blockIdx.y, cg = blockIdx.x, t = threadIdx.x;
    int hm = h_mask[b], wm = w_mask[b];
    float vb = v_b[0];
    float vals[8];
    float psum = 0.f;
    #pragma unroll
    for (int u = 0; u < 8; ++u) {
        int s = u * 256 + t;
        int h = s >> 6, w = s & 63;
        float e = e_acc[b * HWSZ + s] + vb;
        float ex = (h < hm && w < wm) ? expf(e) : 0.f;
        vals[u] = ex;
        psum += ex;
    }
    for (int off = 1; off < 64; off <<= 1) psum += __shfl_xor(psum, off, 64);
    if ((t & 63) == 0) rbuf[t >> 6] = psum;
    __syncthreads();
    float inv = 1.f / (rbuf[0] + rbuf[1] + rbuf[2] + rbuf[3] + 1e-8f);
    #pragma unroll
    for (int u = 0; u < 8; ++u) {
        int s = u * 256 + t;
        float a = vals[u] * inv;
        a_s[s] = a;
        if (cg == 0) alpha_out[b * HWSZ + s] = a;
    }
    __syncthreads();
    int wave = t >> 6, lane = t & 63;
    int c = cg * 4 + wave;
    const float* ep = enc + ((size_t)(b * ENC + c)) * HWSZ;
    float s = 0.f;
    for (int i = lane; i < HWSZ; i += 64) s += ep[i] * a_s[i];
    for (int off = 32; off; off >>= 1) s += __shfl_down(s, off, 64);
    if (lane == 0) ct[b * ENC + c] = s;
}

// ---------------- K7a: gi/gh for GRU2, wide (j,b) mapping -----------------------
__global__ __launch_bounds__(256) void k_gru2a(
    const float* __restrict__ ct, const float* __restrict__ st,
    const float* __restrict__ w_ih, const float* __restrict__ w_hh,
    const float* __restrict__ b_ih, const float* __restrict__ b_hh,
    float* __restrict__ gi, float* __restrict__ gh)
{
    int gid = blockIdx.x * 256 + threadIdx.x;  // 48 blocks
    int j = gid >> 4, b = gid & 15;
    const float* c = ct + b * ENC;
    const float* wi = w_ih + (size_t)j * ENC;
    float si = 0.f;
    for (int k = 0; k < ENC; ++k) si += c[k] * wi[k];
    const float* s = st + b * 256;
    const float* wh = w_hh + (size_t)j * 256;
    float sh = 0.f;
    for (int k = 0; k < 256; ++k) sh += s[k] * wh[k];
    gi[j * 16 + b] = si + b_ih[j];
    gh[j * 16 + b] = sh + b_hh[j];
}

// ---------------- K8: GRU2 gates (fused) + pre = 3 GEMVs + biases ---------------
__global__ __launch_bounds__(256) void k_pre(
    const float* __restrict__ st, const float* __restrict__ gi,
    const float* __restrict__ gh, float* __restrict__ out_hidden,
    const float* __restrict__ emb, const float* __restrict__ ct,
    const float* __restrict__ fc2_w, const float* __restrict__ fc2_b,
    const float* __restrict__ emb2_w, const float* __restrict__ emb2_b,
    const float* __restrict__ wc_w, const float* __restrict__ wc_b,
    float* __restrict__ pre)
{
    __shared__ float h2_s[4096];   // [b][i]
    int t = threadIdx.x;
    #pragma unroll
    for (int q = 0; q < 16; ++q) {
        int idx = q * 256 + t;
        int bb = idx & 15, i = idx >> 4;
        float r = sigm(gi[i * 16 + bb] + gh[i * 16 + bb]);
        float z = sigm(gi[(256 + i) * 16 + bb] + gh[(256 + i) * 16 + bb]);
        float n = tanhf(gi[(512 + i) * 16 + bb] + r * gh[(512 + i) * 16 + bb]);
        float v = (1.f - z) * n + z * st[bb * 256 + i];
        h2_s[bb * 256 + i] = v;
        if (blockIdx.x == 0) out_hidden[bb * 256 + i] = v;
    }
    __syncthreads();
    int gid = blockIdx.x * 256 + t;            // 8 blocks -> 2048 = 128*16
    int j = gid >> 4, b = gid & 15;
    float s = fc2_b[j] + emb2_b[j] + wc_b[j];
    const float* x1 = h2_s + b * 256;
    const float* w1 = fc2_w + (size_t)j * 256;
    for (int k = 0; k < 256; ++k) s += x1[k] * w1[k];
    const float* x2 = emb + b * 256;
    const float* w2 = emb2_w + (size_t)j * 256;
    for (int k = 0; k < 256; ++k) s += x2[k] * w2[k];
    const float* x3 = ct + b * ENC;
    const float* w3 = wc_w + (size_t)j * ENC;
    for (int k = 0; k < ENC; ++k) s += x3[k] * w3[k];
    pre[b * 128 + j] = s;
}

// ---------------- K9: logits = pre @ out_w^T + out_b, wide (j,b) ----------------
__global__ __launch_bounds__(256) void k_logits(
    const float* __restrict__ pre, const float* __restrict__ out_w,
    const float* __restrict__ out_b, float* __restrict__ logits)
{
    int gid = blockIdx.x * 256 + threadIdx.x;  // 313 blocks
    int j = gid >> 4, b = gid & 15;
    if (j >= VOCAB) return;
    const float* wr = out_w + (size_t)j * 128;
    const float* p = pre + b * 128;
    float s = out_b[j];
    for (int k = 0; k < 128; ++k) s += p[k] * wr[k];
    logits[b * VOCAB + j] = s;
}

// ---------------- K10: log_softmax ----------------------------------------------
__global__ __launch_bounds__(256) void k_lsm(
    const float* __restrict__ logits, float* __restrict__ out)
{
    __shared__ float buf[VOCAB];
    __shared__ float rbuf[4];
    int b = blockIdx.x, t = threadIdx.x;
    float mx = -1e30f;
    for (int s = t; s < VOCAB; s += 256) {
        float v = logits[b * VOCAB + s];
        buf[s] = v;
        mx = fmaxf(mx, v);
    }
    for (int off = 1; off < 64; off <<= 1) mx = fmaxf(mx, __shfl_xor(mx, off, 64));
    if ((t & 63) == 0) rbuf[t >> 6] = mx;
    __syncthreads();
    mx = fmaxf(fmaxf(rbuf[0], rbuf[1]), fmaxf(rbuf[2], rbuf[3]));
    __syncthreads();
    float se = 0.f;
    for (int s = t; s < VOCAB; s += 256) se += expf(buf[s] - mx);
    for (int off = 1; off < 64; off <<= 1) se += __shfl_xor(se, off, 64);
    if ((t & 63) == 0) rbuf[t >> 6] = se;
    __syncthreads();
    float lse = mx + logf(rbuf[0] + rbuf[1] + rbuf[2] + rbuf[3]);
    for (int s = t; s < VOCAB; s += 256) out[b * VOCAB + s] = buf[s] - lse;
}

extern "C" void kernel_launch(void* const* d_in, const int* in_sizes, int n_in,
                              void* d_out, int out_size, void* d_ws, size_t ws_size,
                              hipStream_t stream)
{
    const int*   input_a      = (const int*)d_in[0];
    const float* input_hidden = (const float*)d_in[1];
    const float* enc          = (const float*)d_in[2];
    const float* att_in       = (const float*)d_in[3];
    const float* dec_att      = (const float*)d_in[4];
    const int*   h_mask       = (const int*)d_in[5];
    const int*   w_mask       = (const int*)d_in[6];
    const float* emb_w        = (const float*)d_in[11];
    const float* g1_wih       = (const float*)d_in[12];
    const float* g1_whh       = (const float*)d_in[13];
    const float* g1_bih       = (const float*)d_in[14];
    const float* g1_bhh       = (const float*)d_in[15];
    const float* fc1_w        = (const float*)d_in[16];
    const float* fc1_b        = (const float*)d_in[17];
    const float* g2_wih       = (const float*)d_in[18];
    const float* g2_whh       = (const float*)d_in[19];
    const float* g2_bih       = (const float*)d_in[20];
    const float* g2_bhh       = (const float*)d_in[21];
    const float* out_w        = (const float*)d_in[22];
    const float* out_b        = (const float*)d_in[23];
    const float* emb2_w       = (const float*)d_in[24];
    const float* emb2_b       = (const float*)d_in[25];
    const float* c1w          = (const float*)d_in[26];
    const float* c1b          = (const float*)d_in[27];
    const float* ctw          = (const float*)d_in[28];
    const float* ctb          = (const float*)d_in[29];
    const float* fc2_w        = (const float*)d_in[30];
    const float* fc2_b        = (const float*)d_in[31];
    const float* ua_w         = (const float*)d_in[32];
    const float* ua_b         = (const float*)d_in[33];
    const float* uf_w         = (const float*)d_in[34];
    const float* uf_b         = (const float*)d_in[35];
    const float* v_w          = (const float*)d_in[36];
    const float* v_b          = (const float*)d_in[37];
    const float* wc_w         = (const float*)d_in[38];
    const float* wc_b         = (const float*)d_in[39];
    const float* bn_g         = (const float*)d_in[40];
    const float* bn_b         = (const float*)d_in[41];
    const float* bn_rm        = (const float*)d_in[42];
    const float* bn_rv        = (const float*)d_in[43];

    // output layout: log_softmax(16x5000) | hidden_next(16x256) | alpha(16x2048) | att_sum(16x2048)
    float* out        = (float*)d_out;
    float* out_logits = out;
    float* out_hidden = out + 80000;
    float* out_alpha  = out + 84096;
    float* out_attsum = out + 116864;

    // workspace layout
    char* ws = (char*)d_ws;
    unsigned short* et_t  = (unsigned short*)ws;                 // 16.78 MB (NHWC bf16)
    unsigned short* ua_bf = (unsigned short*)(ws + 16777216);    // 0.52 MB
    unsigned short* w_r   = (unsigned short*)(ws + 17301504);    // 1.18 MB
    float* f      = (float*)(ws + 18481152);
    float* st     = f;             // 4096
    float* embv   = f + 4096;      // 4096
    float* addc   = f + 8192;      // 4096
    float* e_ws   = f + 12288;     // 32768
    float* ct     = f + 45056;     // 16384
    float* pre    = f + 61440;     // 2048
    float* logits = f + 63488;     // 80000
    float* gi1    = f + 143488;    // 12288
    float* gh1    = f + 155776;    // 12288
    float* gi2    = f + 168064;    // 12288
    float* gh2    = f + 180352;    // 12288
    float* cs     = f + 192640;    // 256
    float* csh    = f + 192896;    // 256

    k_prep<<<1585, 256, 0, stream>>>(ua_w, ua_bf, ctw, w_r,
                                     att_in, dec_att, c1w, c1b, out_attsum,
                                     ctb, bn_g, bn_b, bn_rm, bn_rv, cs, csh,
                                     input_a, input_hidden, emb_w,
                                     g1_wih, g1_whh, g1_bih, g1_bhh, gi1, gh1,
                                     e_ws);
    k_frontbc<<<16, 256, 0, stream>>>(input_a, emb_w, input_hidden, gi1, gh1,
                                      fc1_w, fc1_b, ua_b, uf_b, st, embv, addc);

    k_et<<<dim3(32, 16), 256, 0, stream>>>(enc, ua_bf, addc, uf_w, out_attsum, et_t);
    k_conv<<<dim3(32, 2, 16), 256, 0, stream>>>(et_t, w_r, cs, csh, v_w, e_ws);

    k_ctalpha<<<dim3(256, 16), 256, 0, stream>>>(enc, e_ws, v_b, h_mask, w_mask,
                                                 out_alpha, ct);
    k_gru2a<<<48, 256, 0, stream>>>(ct, st, g2_wih, g2_whh, g2_bih, g2_bhh, gi2, gh2);
    k_pre<<<8, 256, 0, stream>>>(st, gi2, gh2, out_hidden, embv, ct,
                                 fc2_w, fc2_b, emb2_w, emb2_b, wc_w, wc_b, pre);
    k_logits<<<313, 256, 0, stream>>>(pre, out_w, out_b, logits);
    k_lsm<<<16, 256, 0, stream>>>(logits, out_logits);
}

// Round 5
// 489.354 us; speedup vs baseline: 1.3391x; 1.1838x over previous
//
#include <hip/hip_runtime.h>
#include <hip/hip_bf16.h>

#define HH 32
#define WW 64
#define HWSZ 2048
#define ENC 1024
#define VOCAB 5000

typedef __attribute__((ext_vector_type(8))) short short8;
typedef __attribute__((ext_vector_type(4))) short short4v;
typedef __attribute__((ext_vector_type(4))) float f32x4;

__device__ __forceinline__ float sigm(float x) { return 1.0f / (1.0f + expf(-x)); }

__device__ __forceinline__ unsigned short f2bf(float x) {
    unsigned u = __float_as_uint(x);
    unsigned r = (u + 0x7fff + ((u >> 16) & 1)) >> 16;
    return (unsigned short)r;
}

// split-K-16 helpers: lane l of a 16-lane group covers k = i*64 + l*4 .. +3
template <int NI>
__device__ __forceinline__ float dotk(const float* __restrict__ w,
                                      const float* __restrict__ x, int l) {
    float s = 0.f;
    #pragma unroll
    for (int i = 0; i < NI; ++i) {
        f32x4 wv = *(const f32x4*)(w + i * 64 + l * 4);
        f32x4 xv = *(const f32x4*)(x + i * 64 + l * 4);
        s += wv.x * xv.x + wv.y * xv.y + wv.z * xv.z + wv.w * xv.w;
    }
    return s;
}
__device__ __forceinline__ float red16(float s) {
    s += __shfl_xor(s, 1, 64);
    s += __shfl_xor(s, 2, 64);
    s += __shfl_xor(s, 4, 64);
    s += __shfl_xor(s, 8, 64);
    return s;
}

// ---------------- K0: fused prep: ua->bf16 | wr | attsum | coef | GRU1-a | e=0 --
__global__ __launch_bounds__(256) void k_prep(
    const float* __restrict__ ua_w, unsigned short* __restrict__ ub,
    const float* __restrict__ cw, unsigned short* __restrict__ wr,
    const float* __restrict__ att_in, const float* __restrict__ dec,
    const float* __restrict__ c1w, const float* __restrict__ c1b,
    float* __restrict__ out_attsum,
    const float* __restrict__ wb, const float* __restrict__ g,
    const float* __restrict__ bb, const float* __restrict__ rm,
    const float* __restrict__ rv, float* __restrict__ cs, float* __restrict__ csh,
    const int* __restrict__ input_a, const float* __restrict__ input_hidden,
    const float* __restrict__ emb_w,
    const float* __restrict__ w_ih, const float* __restrict__ w_hh,
    const float* __restrict__ b_ih, const float* __restrict__ b_hh,
    float* __restrict__ gi, float* __restrict__ gh,
    float* __restrict__ e_zero)
{
    int blk = blockIdx.x, t = threadIdx.x;
    if (blk < 1024) {                       // ua_w fp32 -> bf16
        int idx = blk * 256 + t;
        ub[idx] = f2bf(ua_w[idx]);
    } else if (blk < 1280) {                // convtan_w -> w_r[tap][o][ci] bf16
        int idx = (blk - 1024) * 256 + t;   // 65536 = (o,ci)
        const float* p = cw + (size_t)idx * 9;
        #pragma unroll
        for (int k = 0; k < 9; ++k) wr[k * 65536 + idx] = f2bf(p[k]);
    } else if (blk < 1408) {                // att_sum = attention_sum + conv1(dec)
        int idx = (blk - 1280) * 256 + t;   // < 32768
        int b = idx >> 11, hw = idx & 2047;
        int h = hw >> 6, w = hw & 63;
        float s = c1b[0];
        #pragma unroll
        for (int dy = 0; dy < 3; ++dy) {
            int hh = h + dy - 1;
            if ((unsigned)hh < (unsigned)HH) {
                #pragma unroll
                for (int dx = 0; dx < 3; ++dx) {
                    int wi = w + dx - 1;
                    if ((unsigned)wi < (unsigned)WW)
                        s += dec[b * HWSZ + hh * WW + wi] * c1w[dy * 3 + dx];
                }
            }
        }
        out_attsum[idx] = att_in[idx] + s;
    } else if (blk == 1408) {               // BN coef fold
        int c = t;
        float s = g[c] * rsqrtf(rv[c] + 1e-5f);
        cs[c] = s;
        csh[c] = (wb[c] - rm[c]) * s + bb[c];
    } else if (blk < 2177) {                // GRU1 gi/gh split-K (768 blocks)
        int gid = (blk - 1409) * 256 + t;   // 196608 = 768j * 16b * 16l
        int o = gid >> 4, l = gid & 15;
        int j = o >> 4, b = o & 15;
        int ia = input_a[b];
        float si = dotk<4>(w_ih + (size_t)j * 256, emb_w + (size_t)ia * 256, l);
        float sh = dotk<4>(w_hh + (size_t)j * 256, input_hidden + b * 256, l);
        si = red16(si); sh = red16(sh);
        if (l == 0) {
            gi[j * 16 + b] = si + b_ih[j];
            gh[j * 16 + b] = sh + b_hh[j];
        }
    } else {                                // zero e accumulator (128 blocks)
        e_zero[(blk - 2177) * 256 + t] = 0.f;
    }
}

// ---------------- K1b: GRU1 gates + emb passthrough + fc1 -> addc (fused) -------
__global__ __launch_bounds__(256) void k_frontbc(
    const int* __restrict__ input_a, const float* __restrict__ emb_w,
    const float* __restrict__ input_hidden,
    const float* __restrict__ gi, const float* __restrict__ gh,
    const float* __restrict__ fc1_w, const float* __restrict__ fc1_b,
    const float* __restrict__ ua_b, const float* __restrict__ uf_b,
    float* __restrict__ st, float* __restrict__ embv, float* __restrict__ addc)
{
    __shared__ float st_s[256];
    int b = blockIdx.x, i = threadIdx.x;
    float r = sigm(gi[i * 16 + b] + gh[i * 16 + b]);
    float z = sigm(gi[(256 + i) * 16 + b] + gh[(256 + i) * 16 + b]);
    float n = tanhf(gi[(512 + i) * 16 + b] + r * gh[(512 + i) * 16 + b]);
    float h0 = input_hidden[b * 256 + i];
    float v = (1.f - z) * n + z * h0;
    st_s[i] = v;
    st[b * 256 + i] = v;
    embv[b * 256 + i] = emb_w[(size_t)input_a[b] * 256 + i];
    __syncthreads();
    int c = i;
    const float* w = fc1_w + (size_t)c * 256;
    float acc = 0.f;
    for (int k = 0; k < 256; ++k) acc += st_s[k] * w[k];
    addc[b * 256 + c] = acc + fc1_b[c] + ua_b[c] + uf_b[c];
}

// ---------------- K3: et-GEMM via MFMA, N=32/block, grid 64x16 ------------------
// out[c=256][hw=32/block] = ua[c][k=1024] @ enc[k][hw]; NHWC bf16 out.
__global__ __launch_bounds__(256) void k_et(
    const float* __restrict__ enc, const unsigned short* __restrict__ ua_bf,
    const float* __restrict__ addc, const float* __restrict__ uf_w,
    const float* __restrict__ attsum, unsigned short* __restrict__ et)
{
    __shared__ unsigned short Bs[32 * 40];   // [pixel][kk(32, slot-rotated)]
    int t = threadIdx.x;
    int hw0 = blockIdx.x * 32, b = blockIdx.y;
    int wv = t >> 6;
    int l15 = t & 15, quad = (t >> 4) & 3;
    f32x4 acc[4][2];
    #pragma unroll
    for (int i = 0; i < 4; ++i)
        #pragma unroll
        for (int j = 0; j < 2; ++j) acc[i][j] = (f32x4)0.f;

    int sww = t & 31;                        // staging pixel
    int sgrp = t >> 5;                       // 0..7, covers k = sgrp*4 .. +3
    int sp = ((sgrp >> 1) + (sww >> 3)) & 3; // slot rotation (8-k chunks)
    const float* encb = enc + (size_t)b * ENC * HWSZ + hw0 + sww;

    float pf[4];
    {
        const float* ep = encb + (size_t)(sgrp * 4) * HWSZ;
        #pragma unroll
        for (int i = 0; i < 4; ++i) pf[i] = ep[(size_t)i * HWSZ];
    }
    for (int k0 = 0; k0 < ENC; k0 += 32) {
        short4v v;
        #pragma unroll
        for (int i = 0; i < 4; ++i) v[i] = (short)f2bf(pf[i]);
        __syncthreads();
        *(short4v*)(Bs + sww * 40 + sp * 8 + (sgrp & 1) * 4) = v;
        __syncthreads();
        if (k0 + 32 < ENC) {                 // prefetch next tile (overlaps MFMA)
            const float* ep = encb + (size_t)(k0 + 32 + sgrp * 4) * HWSZ;
            #pragma unroll
            for (int i = 0; i < 4; ++i) pf[i] = ep[(size_t)i * HWSZ];
        }
        short8 af[4], bfr[2];
        #pragma unroll
        for (int mt = 0; mt < 4; ++mt)
            af[mt] = *(const short8*)(ua_bf +
                (size_t)(wv * 64 + mt * 16 + l15) * ENC + k0 + quad * 8);
        #pragma unroll
        for (int nt = 0; nt < 2; ++nt) {
            int n = nt * 16 + l15;
            int slot = (quad + (n >> 3)) & 3;
            bfr[nt] = *(const short8*)(Bs + n * 40 + slot * 8);
        }
        #pragma unroll
        for (int mt = 0; mt < 4; ++mt)
            #pragma unroll
            for (int nt = 0; nt < 2; ++nt)
                acc[mt][nt] = __builtin_amdgcn_mfma_f32_16x16x32_bf16(
                    af[mt], bfr[nt], acc[mt][nt], 0, 0, 0);
    }
    // epilogue: + addc[c] + attsum[hw]*uf_w[c], store NHWC bf16
    float at[2];
    #pragma unroll
    for (int nt = 0; nt < 2; ++nt) at[nt] = attsum[b * HWSZ + hw0 + nt * 16 + l15];
    #pragma unroll
    for (int mt = 0; mt < 4; ++mt) {
        int cb = wv * 64 + mt * 16 + quad * 4;
        float ad[4], uw[4];
        #pragma unroll
        for (int r = 0; r < 4; ++r) { ad[r] = addc[b * 256 + cb + r]; uw[r] = uf_w[cb + r]; }
        #pragma unroll
        for (int nt = 0; nt < 2; ++nt) {
            ushort4 pk;
            pk.x = f2bf(acc[mt][nt][0] + ad[0] + at[nt] * uw[0]);
            pk.y = f2bf(acc[mt][nt][1] + ad[1] + at[nt] * uw[1]);
            pk.z = f2bf(acc[mt][nt][2] + ad[2] + at[nt] * uw[2]);
            pk.w = f2bf(acc[mt][nt][3] + ad[3] + at[nt] * uw[3]);
            *(ushort4*)(et + (size_t)(b * HWSZ + hw0 + nt * 16 + l15) * 256 + cb) = pk;
        }
    }
}

// ---------------- K4: conv3x3 implicit-GEMM MFMA + BN + tanh + v-dot ------------
// Grid (h, c-half, b): block = [128 c_out][64 w]; 4 waves, M=32/wave, 8 MFMA/kc.
__global__ __launch_bounds__(256) void k_conv(
    const unsigned short* __restrict__ et, const unsigned short* __restrict__ wr,
    const float* __restrict__ cs, const float* __restrict__ csh,
    const float* __restrict__ v_w, float* __restrict__ e_out)
{
    __shared__ unsigned short Ls[66 * 264];  // [pixel 0..65][ci 256 pad->264]
    __shared__ float red[64][17];
    int t = threadIdx.x;
    int h = blockIdx.x, c0 = blockIdx.y * 128, b = blockIdx.z;
    int wv = t >> 6, l15 = t & 15, quad = (t >> 4) & 3;
    f32x4 acc[2][4];
    #pragma unroll
    for (int i = 0; i < 2; ++i)
        #pragma unroll
        for (int j = 0; j < 4; ++j) acc[i][j] = (f32x4)0.f;

    for (int dy = 0; dy < 3; ++dy) {
        int hr = h + dy - 1;
        if ((unsigned)hr >= (unsigned)HH) continue;   // block-uniform
        __syncthreads();
        const unsigned short* rowp = et + (size_t)(b * HH + hr) * WW * 256;
        for (int idx = t; idx < 2112; idx += 256) {   // 66 pixels x 32 chunks
            int p = idx >> 5, s = idx & 31;
            short8 v;
            if (p == 0 || p == 65) v = (short8)0;
            else v = *(const short8*)(rowp + (p - 1) * 256 + s * 8);
            *(short8*)(Ls + p * 264 + s * 8) = v;
        }
        __syncthreads();
        for (int dx = 0; dx < 3; ++dx) {
            int tap = dy * 3 + dx;
            const unsigned short* wrt = wr + (size_t)tap * 65536;
            #pragma unroll
            for (int kc = 0; kc < 8; ++kc) {
                short8 af[2], bfr[4];
                #pragma unroll
                for (int mt = 0; mt < 2; ++mt)
                    af[mt] = *(const short8*)(wrt +
                        (size_t)(c0 + wv * 32 + mt * 16 + l15) * 256 + kc * 32 + quad * 8);
                #pragma unroll
                for (int nt = 0; nt < 4; ++nt) {
                    int wrow = nt * 16 + l15 + dx;     // 0..65, pads zero
                    bfr[nt] = *(const short8*)(Ls + wrow * 264 + kc * 32 + quad * 8);
                }
                #pragma unroll
                for (int mt = 0; mt < 2; ++mt)
                    #pragma unroll
                    for (int nt = 0; nt < 4; ++nt)
                        acc[mt][nt] = __builtin_amdgcn_mfma_f32_16x16x32_bf16(
                            af[mt], bfr[nt], acc[mt][nt], 0, 0, 0);
            }
        }
    }
    // epilogue: y = acc*cs + csh; partial e = sum tanh(y)*v_w over this lane's c
    float p[4] = {0.f, 0.f, 0.f, 0.f};
    #pragma unroll
    for (int mt = 0; mt < 2; ++mt) {
        int cb = c0 + wv * 32 + mt * 16 + quad * 4;
        #pragma unroll
        for (int r = 0; r < 4; ++r) {
            float sc = cs[cb + r], sh = csh[cb + r], vw = v_w[cb + r];
            #pragma unroll
            for (int nt = 0; nt < 4; ++nt) {
                float x = acc[mt][nt][r] * sc + sh;
                p[nt] += tanhf(x) * vw;
            }
        }
    }
    __syncthreads();
    #pragma unroll
    for (int nt = 0; nt < 4; ++nt) red[nt * 16 + l15][wv * 4 + quad] = p[nt];
    __syncthreads();
    if (t < 64) {
        float s = 0.f;
        #pragma unroll
        for (int i = 0; i < 16; ++i) s += red[t][i];
        atomicAdd(&e_out[(b * HH + h) * WW + t], s);   // two c-halves accumulate
    }
}

// ---------------- K5+K6 fused: softmax(e)->alpha (LDS) + ct reduction -----------
__global__ __launch_bounds__(256) void k_ctalpha(
    const float* __restrict__ enc, const float* __restrict__ e_acc,
    const float* __restrict__ v_b,
    const int* __restrict__ h_mask, const int* __restrict__ w_mask,
    float* __restrict__ alpha_out, float* __restrict__ ct)
{
    __shared__ float a_s[HWSZ];
    __shared__ float rbuf[4];
    int b = blockIdx.y, cg = blockIdx.x, t = threadIdx.x;
    int hm = h_mask[b], wm = w_mask[b];
    float vb = v_b[0];
    float vals[8];
    float psum = 0.f;
    #pragma unroll
    for (int u = 0; u < 8; ++u) {
        int s = u * 256 + t;
        int h = s >> 6, w = s & 63;
        float e = e_acc[b * HWSZ + s] + vb;
        float ex = (h < hm && w < wm) ? expf(e) : 0.f;
        vals[u] = ex;
        psum += ex;
    }
    for (int off = 1; off < 64; off <<= 1) psum += __shfl_xor(psum, off, 64);
    if ((t & 63) == 0) rbuf[t >> 6] = psum;
    __syncthreads();
    float inv = 1.f / (rbuf[0] + rbuf[1] + rbuf[2] + rbuf[3] + 1e-8f);
    #pragma unroll
    for (int u = 0; u < 8; ++u) {
        int s = u * 256 + t;
        float a = vals[u] * inv;
        a_s[s] = a;
        if (cg == 0) alpha_out[b * HWSZ + s] = a;
    }
    __syncthreads();
    int wave = t >> 6, lane = t & 63;
    int c = cg * 4 + wave;
    const float* ep = enc + ((size_t)(b * ENC + c)) * HWSZ;
    float s = 0.f;
    for (int i = lane; i < HWSZ; i += 64) s += ep[i] * a_s[i];
    for (int off = 32; off; off >>= 1) s += __shfl_down(s, off, 64);
    if (lane == 0) ct[b * ENC + c] = s;
}

// ---------------- K7a: gi/gh for GRU2, split-K-16 (768 blocks) ------------------
__global__ __launch_bounds__(256) void k_gru2a(
    const float* __restrict__ ct, const float* __restrict__ st,
    const float* __restrict__ w_ih, const float* __restrict__ w_hh,
    const float* __restrict__ b_ih, const float* __restrict__ b_hh,
    float* __restrict__ gi, float* __restrict__ gh)
{
    int gid = blockIdx.x * 256 + threadIdx.x;
    int o = gid >> 4, l = gid & 15;
    int j = o >> 4, b = o & 15;
    float si = dotk<16>(w_ih + (size_t)j * ENC, ct + b * ENC, l);
    float sh = dotk<4>(w_hh + (size_t)j * 256, st + b * 256, l);
    si = red16(si); sh = red16(sh);
    if (l == 0) {
        gi[j * 16 + b] = si + b_ih[j];
        gh[j * 16 + b] = sh + b_hh[j];
    }
}

// ---------------- K7b: GRU2 gates -> h2 / hidden_next ---------------------------
__global__ __launch_bounds__(256) void k_gates2(
    const float* __restrict__ st, const float* __restrict__ gi,
    const float* __restrict__ gh, float* __restrict__ h2,
    float* __restrict__ out_hidden)
{
    int b = blockIdx.x, i = threadIdx.x;
    float r = sigm(gi[i * 16 + b] + gh[i * 16 + b]);
    float z = sigm(gi[(256 + i) * 16 + b] + gh[(256 + i) * 16 + b]);
    float n = tanhf(gi[(512 + i) * 16 + b] + r * gh[(512 + i) * 16 + b]);
    float v = (1.f - z) * n + z * st[b * 256 + i];
    h2[b * 256 + i] = v;
    out_hidden[b * 256 + i] = v;
}

// ---------------- K8: pre = h2@fc2^T + emb@emb2^T + ct@wc^T, split-K-16 ---------
__global__ __launch_bounds__(256) void k_pre(
    const float* __restrict__ h2, const float* __restrict__ emb,
    const float* __restrict__ ct,
    const float* __restrict__ fc2_w, const float* __restrict__ fc2_b,
    const float* __restrict__ emb2_w, const float* __restrict__ emb2_b,
    const float* __restrict__ wc_w, const float* __restrict__ wc_b,
    float* __restrict__ pre)
{
    int gid = blockIdx.x * 256 + threadIdx.x;  // 128 blocks: 128j*16b*16l
    int o = gid >> 4, l = gid & 15;
    int j = o >> 4, b = o & 15;
    float s = dotk<4>(fc2_w + (size_t)j * 256, h2 + b * 256, l)
            + dotk<4>(emb2_w + (size_t)j * 256, emb + b * 256, l)
            + dotk<16>(wc_w + (size_t)j * ENC, ct + b * ENC, l);
    s = red16(s);
    if (l == 0) pre[b * 128 + j] = s + fc2_b[j] + emb2_b[j] + wc_b[j];
}

// ---------------- K9: logits = pre @ out_w^T + out_b, split-K-16 ----------------
__global__ __launch_bounds__(256) void k_logits(
    const float* __restrict__ pre, const float* __restrict__ out_w,
    const float* __restrict__ out_b, float* __restrict__ logits)
{
    int gid = blockIdx.x * 256 + threadIdx.x;  // 5000 blocks: 5000j*16b*16l
    int o = gid >> 4, l = gid & 15;
    int j = o >> 4, b = o & 15;
    float s = dotk<2>(out_w + (size_t)j * 128, pre + b * 128, l);
    s = red16(s);
    if (l == 0) logits[b * VOCAB + j] = s + out_b[j];
}

// ---------------- K10: log_softmax ----------------------------------------------
__global__ __launch_bounds__(256) void k_lsm(
    const float* __restrict__ logits, float* __restrict__ out)
{
    __shared__ float buf[VOCAB];
    __shared__ float rbuf[4];
    int b = blockIdx.x, t = threadIdx.x;
    float mx = -1e30f;
    for (int s = t; s < VOCAB; s += 256) {
        float v = logits[b * VOCAB + s];
        buf[s] = v;
        mx = fmaxf(mx, v);
    }
    for (int off = 1; off < 64; off <<= 1) mx = fmaxf(mx, __shfl_xor(mx, off, 64));
    if ((t & 63) == 0) rbuf[t >> 6] = mx;
    __syncthreads();
    mx = fmaxf(fmaxf(rbuf[0], rbuf[1]), fmaxf(rbuf[2], rbuf[3]));
    __syncthreads();
    float se = 0.f;
    for (int s = t; s < VOCAB; s += 256) se += expf(buf[s] - mx);
    for (int off = 1; off < 64; off <<= 1) se += __shfl_xor(se, off, 64);
    if ((t & 63) == 0) rbuf[t >> 6] = se;
    __syncthreads();
    float lse = mx + logf(rbuf[0] + rbuf[1] + rbuf[2] + rbuf[3]);
    for (int s = t; s < VOCAB; s += 256) out[b * VOCAB + s] = buf[s] - lse;
}

extern "C" void kernel_launch(void* const* d_in, const int* in_sizes, int n_in,
                              void* d_out, int out_size, void* d_ws, size_t ws_size,
                              hipStream_t stream)
{
    const int*   input_a      = (const int*)d_in[0];
    const float* input_hidden = (const float*)d_in[1];
    const float* enc          = (const float*)d_in[2];
    const float* att_in       = (const float*)d_in[3];
    const float* dec_att      = (const float*)d_in[4];
    const int*   h_mask       = (const int*)d_in[5];
    const int*   w_mask       = (const int*)d_in[6];
    const float* emb_w        = (const float*)d_in[11];
    const float* g1_wih       = (const float*)d_in[12];
    const float* g1_whh       = (const float*)d_in[13];
    const float* g1_bih       = (const float*)d_in[14];
    const float* g1_bhh       = (const float*)d_in[15];
    const float* fc1_w        = (const float*)d_in[16];
    const float* fc1_b        = (const float*)d_in[17];
    const float* g2_wih       = (const float*)d_in[18];
    const float* g2_whh       = (const float*)d_in[19];
    const float* g2_bih       = (const float*)d_in[20];
    const float* g2_bhh       = (const float*)d_in[21];
    const float* out_w        = (const float*)d_in[22];
    const float* out_b        = (const float*)d_in[23];
    const float* emb2_w       = (const float*)d_in[24];
    const float* emb2_b       = (const float*)d_in[25];
    const float* c1w          = (const float*)d_in[26];
    const float* c1b          = (const float*)d_in[27];
    const float* ctw          = (const float*)d_in[28];
    const float* ctb          = (const float*)d_in[29];
    const float* fc2_w        = (const float*)d_in[30];
    const float* fc2_b        = (const float*)d_in[31];
    const float* ua_w         = (const float*)d_in[32];
    const float* ua_b         = (const float*)d_in[33];
    const float* uf_w         = (const float*)d_in[34];
    const float* uf_b         = (const float*)d_in[35];
    const float* v_w          = (const float*)d_in[36];
    const float* v_b          = (const float*)d_in[37];
    const float* wc_w         = (const float*)d_in[38];
    const float* wc_b         = (const float*)d_in[39];
    const float* bn_g         = (const float*)d_in[40];
    const float* bn_b         = (const float*)d_in[41];
    const float* bn_rm        = (const float*)d_in[42];
    const float* bn_rv        = (const float*)d_in[43];

    // output layout: log_softmax(16x5000) | hidden_next(16x256) | alpha(16x2048) | att_sum(16x2048)
    float* out        = (float*)d_out;
    float* out_logits = out;
    float* out_hidden = out + 80000;
    float* out_alpha  = out + 84096;
    float* out_attsum = out + 116864;

    // workspace layout
    char* ws = (char*)d_ws;
    unsigned short* et_t  = (unsigned short*)ws;                 // 16.78 MB (NHWC bf16)
    unsigned short* ua_bf = (unsigned short*)(ws + 16777216);    // 0.52 MB
    unsigned short* w_r   = (unsigned short*)(ws + 17301504);    // 1.18 MB
    float* f      = (float*)(ws + 18481152);
    float* st     = f;             // 4096
    float* embv   = f + 4096;      // 4096
    float* addc   = f + 8192;      // 4096
    float* e_ws   = f + 12288;     // 32768
    float* ct     = f + 45056;     // 16384
    float* h2     = f + 61440;     // 4096
    float* pre    = f + 65536;     // 2048
    float* logits = f + 67584;     // 80000
    float* gi1    = f + 147584;    // 12288
    float* gh1    = f + 159872;    // 12288
    float* gi2    = f + 172160;    // 12288
    float* gh2    = f + 184448;    // 12288
    float* cs     = f + 196736;    // 256
    float* csh    = f + 196992;    // 256

    k_prep<<<2305, 256, 0, stream>>>(ua_w, ua_bf, ctw, w_r,
                                     att_in, dec_att, c1w, c1b, out_attsum,
                                     ctb, bn_g, bn_b, bn_rm, bn_rv, cs, csh,
                                     input_a, input_hidden, emb_w,
                                     g1_wih, g1_whh, g1_bih, g1_bhh, gi1, gh1,
                                     e_ws);
    k_frontbc<<<16, 256, 0, stream>>>(input_a, emb_w, input_hidden, gi1, gh1,
                                      fc1_w, fc1_b, ua_b, uf_b, st, embv, addc);

    k_et<<<dim3(64, 16), 256, 0, stream>>>(enc, ua_bf, addc, uf_w, out_attsum, et_t);
    k_conv<<<dim3(32, 2, 16), 256, 0, stream>>>(et_t, w_r, cs, csh, v_w, e_ws);

    k_ctalpha<<<dim3(256, 16), 256, 0, stream>>>(enc, e_ws, v_b, h_mask, w_mask,
                                                 out_alpha, ct);
    k_gru2a<<<768, 256, 0, stream>>>(ct, st, g2_wih, g2_whh, g2_bih, g2_bhh, gi2, gh2);
    k_gates2<<<16, 256, 0, stream>>>(st, gi2, gh2, h2, out_hidden);
    k_pre<<<128, 256, 0, stream>>>(h2, embv, ct, fc2_w, fc2_b, emb2_w, emb2_b,
                                   wc_w, wc_b, pre);
    k_logits<<<5000, 256, 0, stream>>>(pre, out_w, out_b, logits);
    k_lsm<<<16, 256, 0, stream>>>(logits, out_logits);
}